// Round 5
// baseline (220.916 us; speedup 1.0000x reference)
//
#include <hip/hip_runtime.h>

#define H_ 56
#define W_ 56
#define HW_ 3136
#define CIN_ 256
#define COUT_ 256

typedef __attribute__((ext_vector_type(8))) short short8;
typedef __attribute__((ext_vector_type(4))) float f32x4;

__device__ __forceinline__ int swz(int n) { return ((n ^ (n >> 3)) & 7) << 3; }

__device__ __forceinline__ unsigned short f2bf(float f) {
  union { float f; unsigned int i; } v; v.f = f;
  unsigned int b = v.i + (0x7fffu + ((v.i >> 16) & 1u));  // RNE
  return (unsigned short)(b >> 16);
}

__global__ __launch_bounds__(256, 2)
void shiftconv_gemm(const float* __restrict__ x,
                    const float* __restrict__ wgt,
                    const float* __restrict__ gamma,
                    const float* __restrict__ beta,
                    const float* __restrict__ rmean,
                    const float* __restrict__ rvar,
                    float* __restrict__ out)
{
  // A: W tile [m=128][k=64] bf16, B: Xshift tile [n=128][k=64] bf16,
  // both k-contiguous, XOR-swizzled columns (16B-aligned, <=2-way banks).
  __shared__ unsigned short Alds[128 * 64];
  __shared__ unsigned short Blds[128 * 64];
  __shared__ float bnp[256];   // interleaved (inv, add) per local o

  const int t    = threadIdx.x;
  const int bn   = blockIdx.x;   // 784 n-tiles of 128
  const int bm   = blockIdx.y;   // 2 m-tiles of 128
  const int lane = t & 63;
  const int wv   = t >> 6;
  const int wm   = wv >> 1;      // wave m-half
  const int wn   = wv & 1;       // wave n-half
  const int quad = lane >> 4;
  const int l15  = lane & 15;

  if (t < 128) {
    int o = bm * 128 + t;
    float inv = gamma[o] * rsqrtf(rvar[o] + 1e-5f);
    bnp[2 * t]     = inv;
    bnp[2 * t + 1] = beta[o] - rmean[o] * inv;
  }

  // ---- B staging decode (constant across K loop) ----
  const int chunk  = t & 15;          // 16 chunks of 8 n
  const int krow   = t >> 4;          // 0..15
  const int nloc0  = chunk * 8;
  const int nglob0 = bn * 128 + nloc0;
  const int bidx   = nglob0 / HW_;
  const int rem    = nglob0 - bidx * HW_;
  const int hh     = rem / W_;
  const int w0     = rem - hh * W_;   // multiple of 8
  const size_t xb  = (size_t)bidx * CIN_ * HW_;

  // ---- A staging decode ----
  const int kc  = t & 7;
  const int am0 = t >> 3;             // 0..31

  f32x4 acc[4][4];
  #pragma unroll
  for (int i = 0; i < 4; ++i)
    #pragma unroll
    for (int j = 0; j < 4; ++j)
      acc[i][j] = (f32x4){0.f, 0.f, 0.f, 0.f};

  for (int k0 = 0; k0 < CIN_; k0 += 64) {
    // ---- stage A (weights, fp32 row-major source -> bf16 LDS) ----
    #pragma unroll
    for (int p = 0; p < 4; ++p) {
      int m = am0 + 32 * p;
      int o = bm * 128 + m;
      const float* src = wgt + (size_t)o * CIN_ + k0 + kc * 8;
      float4 f0 = *(const float4*)(src);
      float4 f1 = *(const float4*)(src + 4);
      union { uint4 v; unsigned short s[8]; } pk;
      pk.s[0] = f2bf(f0.x); pk.s[1] = f2bf(f0.y);
      pk.s[2] = f2bf(f0.z); pk.s[3] = f2bf(f0.w);
      pk.s[4] = f2bf(f1.x); pk.s[5] = f2bf(f1.y);
      pk.s[6] = f2bf(f1.z); pk.s[7] = f2bf(f1.w);
      *(uint4*)(&Alds[m * 64 + ((kc * 8) ^ swz(m))]) = pk.v;
    }
    // ---- stage B (shift-gathered fp32 x -> bf16), transpose via LDS scatter ----
    #pragma unroll
    for (int p = 0; p < 4; ++p) {
      int kk = krow + 16 * p;         // k within tile, 0..63
      int c  = k0 + kk;
      int dx, dy;
      if (c < 102)      { if (c < 51) { dx = 0; dy = 0; } else { dx = 1; dy = 0; } }
      else if (c < 153) { dx = -1; dy = 0; }
      else if (c < 204) { dx = 0;  dy = 1; }
      else              { dx = 0;  dy = -1; }
      int h2 = hh - dy;
      float vals[8];
      if ((unsigned)h2 < (unsigned)H_) {
        const float* row = x + xb + (size_t)c * HW_ + h2 * W_;
        float4 a = *(const float4*)(row + w0);
        float4 b = *(const float4*)(row + w0 + 4);
        float s[8] = {a.x, a.y, a.z, a.w, b.x, b.y, b.z, b.w};
        if (dx == 0) {
          #pragma unroll
          for (int i = 0; i < 8; ++i) vals[i] = s[i];
        } else if (dx == 1) {         // y[w] = x[w-1]
          #pragma unroll
          for (int i = 7; i >= 1; --i) vals[i] = s[i - 1];
          vals[0] = (w0 > 0) ? row[w0 - 1] : 0.0f;
        } else {                      // dx == -1: y[w] = x[w+1]
          #pragma unroll
          for (int i = 0; i < 7; ++i) vals[i] = s[i + 1];
          vals[7] = (w0 + 8 < W_) ? row[w0 + 8] : 0.0f;
        }
      } else {
        #pragma unroll
        for (int i = 0; i < 8; ++i) vals[i] = 0.0f;
      }
      #pragma unroll
      for (int i = 0; i < 8; ++i) {
        int nl = nloc0 + i;
        Blds[nl * 64 + (kk ^ swz(nl))] = f2bf(vals[i]);
      }
    }
    __syncthreads();
    // ---- MFMA compute: 2 k-steps of 32 ----
    #pragma unroll
    for (int ks = 0; ks < 2; ++ks) {
      int kb = ks * 32 + quad * 8;
      short8 af[4], bf[4];
      #pragma unroll
      for (int f = 0; f < 4; ++f) {
        int ml = wm * 64 + f * 16 + l15;
        af[f] = *(const short8*)(&Alds[ml * 64 + (kb ^ swz(ml))]);
        int nl = wn * 64 + f * 16 + l15;
        bf[f] = *(const short8*)(&Blds[nl * 64 + (kb ^ swz(nl))]);
      }
      #pragma unroll
      for (int mf = 0; mf < 4; ++mf)
        #pragma unroll
        for (int nf = 0; nf < 4; ++nf)
          acc[mf][nf] = __builtin_amdgcn_mfma_f32_16x16x32_bf16(
              af[mf], bf[nf], acc[mf][nf], 0, 0, 0);
    }
    __syncthreads();
  }

  // ---- epilogue: BN + ReLU + fp32 store ----
  size_t nbase[4];
  #pragma unroll
  for (int nf = 0; nf < 4; ++nf) {
    int ng  = bn * 128 + wn * 64 + nf * 16 + l15;
    int b2  = ng / HW_;
    int hw2 = ng - b2 * HW_;
    nbase[nf] = (size_t)b2 * COUT_ * HW_ + hw2;
  }
  #pragma unroll
  for (int mf = 0; mf < 4; ++mf) {
    int mloc = wm * 64 + mf * 16 + quad * 4;   // local o for reg r=0
    float inv[4], add[4];
    #pragma unroll
    for (int r = 0; r < 4; ++r) {
      inv[r] = bnp[2 * (mloc + r)];
      add[r] = bnp[2 * (mloc + r) + 1];
    }
    size_t obase = (size_t)(bm * 128 + mloc) * HW_;
    #pragma unroll
    for (int nf = 0; nf < 4; ++nf) {
      #pragma unroll
      for (int r = 0; r < 4; ++r) {
        float v = acc[mf][nf][r] * inv[r] + add[r];
        out[nbase[nf] + obase + (size_t)r * HW_] = fmaxf(v, 0.0f);
      }
    }
  }
}

extern "C" void kernel_launch(void* const* d_in, const int* in_sizes, int n_in,
                              void* d_out, int out_size, void* d_ws, size_t ws_size,
                              hipStream_t stream) {
  const float* x     = (const float*)d_in[0];
  const float* wgt   = (const float*)d_in[1];
  const float* gamma = (const float*)d_in[2];
  const float* beta  = (const float*)d_in[3];
  const float* rmean = (const float*)d_in[4];
  const float* rvar  = (const float*)d_in[5];
  float* out = (float*)d_out;
  dim3 grid(784, 2);
  shiftconv_gemm<<<grid, dim3(256), 0, stream>>>(x, wgt, gamma, beta, rmean, rvar, out);
}